// Round 1
// baseline (98.956 us; speedup 1.0000x reference)
//
#include <hip/hip_runtime.h>

#define T 8192
#define BATCH 512
#define NTH 1024
#define EPT 8
#define NW 16

__global__ void ratio_kernel(const float* __restrict__ stats, float* __restrict__ ws) {
    int tid = threadIdx.x;               // 512 threads, one per row
    float v = stats[tid * 5 + 4];
    v = fminf(fmaxf(v, 0.f), 1.f);
#pragma unroll
    for (int off = 32; off; off >>= 1) v = fmaxf(v, __shfl_xor(v, off));
    __shared__ float s[8];
    int lane = tid & 63, wid = tid >> 6;
    if (lane == 0) s[wid] = v;
    __syncthreads();
    if (tid == 0) {
        float m = s[0];
#pragma unroll
        for (int w = 1; w < 8; w++) m = fmaxf(m, s[w]);
        ws[0] = m;
    }
}

template <int N>
__device__ __forceinline__ void block_reduce(float (&v)[N], float* s_red, float* s_bc) {
    int lane = threadIdx.x & 63, wid = threadIdx.x >> 6;
#pragma unroll
    for (int j = 0; j < N; j++) {
        float x = v[j];
#pragma unroll
        for (int off = 32; off; off >>= 1) x += __shfl_xor(x, off);
        if (lane == 0) s_red[wid * N + j] = x;
    }
    __syncthreads();
    if (threadIdx.x < N) {
        float s = 0.f;
#pragma unroll
        for (int w = 0; w < NW; w++) s += s_red[w * N + threadIdx.x];
        s_bc[threadIdx.x] = s;
    }
    __syncthreads();
}

__global__ __launch_bounds__(NTH) void teacher_kernel(
    const float* __restrict__ dur, const float* __restrict__ stats,
    const float* __restrict__ trace, const float* __restrict__ mask,
    const float* __restrict__ cue, const float* __restrict__ ws,
    float* __restrict__ out)
{
    const int row = blockIdx.x;
    if (row >= BATCH) return;
    const int tid = threadIdx.x;
    const int lane = tid & 63, wid = tid >> 6;

    __shared__ float s_row[T];            // 32 KB
    __shared__ unsigned s_hist[NW * 256]; // 16 KB
    __shared__ float s_red[NW * 12];
    __shared__ float s_bc[16];
    __shared__ unsigned s_sel[4];
    __shared__ unsigned s_wu[NW];

    const size_t BT = (size_t)BATCH * T;
    const size_t rbase = (size_t)row * T;
    const float* drow = dur + rbase;
    const float* mrow = mask + rbase;
    const float* crow = cue + rbase;
    const float4* trow = (const float4*)(trace + rbase * 4);

    float* o_spe = out;
    float* o_pae = out + BT;
    float* o_sb  = out + 2 * BT;
    float* o_pb  = out + 2 * BT + BATCH;
    float* o_al  = out + 2 * BT + 2 * BATCH;
    float* o_cf  = out + 3 * BT + 2 * BATCH;
    float4* o_tc = ((float4*)(out + 3 * BT + 3 * BATCH)) + rbase;
    float* o_pc  = out + 7 * BT + 3 * BATCH;
    float* o_bk  = out + 8 * BT + 3 * BATCH;

    float durr[EPT], cuer[EPT], t0r[EPT], t1r[EPT], t2r[EPT], t3r[EPT];

    // ---- Phase 1: single full read of all inputs, write trace_ctx, 12 masked sums
    float acc[12];
#pragma unroll
    for (int j = 0; j < 12; j++) acc[j] = 0.f;
#pragma unroll
    for (int i = 0; i < EPT; i++) {
        int t = i * NTH + tid;
        float m = mrow[t];
        float d = drow[t];
        float c = crow[t];
        float4 tr = trow[t];
        durr[i] = d; cuer[i] = c;
        t0r[i] = tr.x; t1r[i] = tr.y; t2r[i] = tr.z; t3r[i] = tr.w;
        o_tc[t] = make_float4(tr.x * m, tr.y * m, tr.z * m, tr.w * m);
        acc[0] += m;            acc[1] += d * m;
        acc[2] += tr.x * m;     acc[3] += tr.x * tr.x * m;
        acc[4] += tr.y * m;     acc[5] += tr.y * tr.y * m;
        acc[6] += tr.z * m;     acc[7] += tr.z * tr.z * m;
        acc[8] += tr.w * m;     acc[9] += tr.w * tr.w * m;
        acc[10] += c * m;       acc[11] += c * c * m;
    }
    block_reduce<12>(acc, s_red, s_bc);
    const float visible = fmaxf(s_bc[0], 1.f);
    const float sum_d = s_bc[1];
    const float mean0 = s_bc[2] / visible, ex20 = s_bc[3] / visible;
    const float mean1 = s_bc[4] / visible, ex21 = s_bc[5] / visible;
    const float mean2 = s_bc[6] / visible, ex22 = s_bc[7] / visible;
    const float mean3 = s_bc[8] / visible, ex23 = s_bc[9] / visible;
    const float meanc = s_bc[10] / visible, ex2c = s_bc[11] / visible;

    const float var1_raw = ex21 - mean1 * mean1;
    const float istd0 = 1.f / sqrtf(fmaxf(ex20 - mean0 * mean0, 1e-6f));
    const float istd1 = 1.f / sqrtf(fmaxf(var1_raw, 1e-6f));
    const float istd2 = 1.f / sqrtf(fmaxf(ex22 - mean2 * mean2, 1e-6f));
    const float istd3 = 1.f / sqrtf(fmaxf(ex23 - mean3 * mean3, 1e-6f));
    const float istdc = 1.f / sqrtf(fmaxf(ex2c - meanc * meanc, 1e-6f));

    const int L = (int)(visible + 0.5f);

    const float st0 = stats[row * 5 + 0], st1 = stats[row * 5 + 1];
    const float st2 = stats[row * 5 + 2], st4 = stats[row * 5 + 4];

    const float src_total = fmaxf(sum_d, 1.f);
    const float src_mean = src_total / visible;
    const float ref_ms = fmaxf(st2, 1.f);
    const float rate_scale = fminf(fmaxf(ref_ms / fmaxf(src_mean, 1.f), 0.55f), 1.95f);
    const float speech_budget = src_total * rate_scale;
    const float pause_ratio = fminf(fmaxf(st0, 0.f), 0.49f);
    const float boundary_ratio = fminf(fmaxf(st4, 0.f), 1.f);
    const float mean_pause = fmaxf(st1, 0.f);
    const float pfr = speech_budget * pause_ratio / fmaxf(1.f - pause_ratio, 0.2f);
    const float pfe = visible * boundary_ratio * mean_pause;
    float pause_budget = fmaxf(0.35f * pfr + 0.65f * pfe, 0.f);
    pause_budget = fminf(pause_budget, speech_budget * 0.8f);

    float conf = 0.2f + 0.3f * fminf(fmaxf(st0, 0.f), 1.f)
               + 0.25f * fminf(fmaxf(st4, 0.f), 1.f)
               + 0.2f * mean2
               + 0.1f * expf(-fmaxf(var1_raw, 0.f)) + 0.05f;
    conf = fminf(fmaxf(conf, 0.05f), 1.f);

    const float ratio = fminf(fmaxf(fmaxf(0.3f, ws[0]), 0.f), 1.f);
    int kint = (int)rintf(visible * ratio);
    kint = max(1, min(kint, L));

    // ---- Phase 2: sp/rb + cosine pieces
    float sp[EPT], rb[EPT];
    float acc3[3] = {0.f, 0.f, 0.f};
#pragma unroll
    for (int i = 0; i < EPT; i++) {
        int t = i * NTH + tid;
        float spv = 0.f, rbv = 0.f;
        if (t < L) {
            spv = fminf(fmaxf((cuer[i] - meanc) * istdc, -1.5f), 1.5f);
            rbv = (t2r[i] - mean2) * istd2;
        }
        sp[i] = spv; rb[i] = rbv;
        acc3[0] += spv * rbv; acc3[1] += spv * spv; acc3[2] += rbv * rbv;
    }
    block_reduce<3>(acc3, s_red, s_bc);
    {
        float dotv = s_bc[0];
        float xn = sqrtf(fmaxf(s_bc[1], 1e-6f));
        float yn = sqrtf(fmaxf(s_bc[2], 1e-6f));
        float agree = fminf(fmaxf(dotv / fmaxf(xn * yn, 1e-6f), -1.f), 1.f);
        float gate = 1.f / (1.f + expf(-(agree - 0.15f) * 4.f));
        gate = 0.05f + 0.5f * gate;
        s_bc[15] = 0.35f * gate;   // broadcast prior coefficient (uniform anyway)
    }
    __syncthreads();
    const float pcoef = s_bc[15];

    // ---- Phase 3a: unsmoothed speech scores -> LDS
#pragma unroll
    for (int i = 0; i < EPT; i++) {
        int t = i * NTH + tid;
        float v = 0.f;
        if (t < L) {
            float z1 = (t1r[i] - mean1) * istd1;
            float z3 = (t3r[i] - mean3) * istd3;
            float pf = (t == T - 1) ? 1.f : crow[t + 1];
            v = expf(log1pf(fmaxf(durr[i], 0.f)) + 0.45f * z1 + 0.3f * z3 + 0.2f * pf);
        }
        s_row[t] = v;
    }
    __syncthreads();

    // ---- Phase 3b: smooth3 * mask, sum
    float sm[EPT];
    float acc1[1] = {0.f};
#pragma unroll
    for (int i = 0; i < EPT; i++) {
        int t = i * NTH + tid;
        float v = 0.f;
        if (t < L) {
            float a = (t > 0) ? s_row[t - 1] : 0.f;
            float b = s_row[t];
            float c = (t < T - 1) ? s_row[t + 1] : 0.f;
            v = (a + b + c) / 3.0f;
        }
        sm[i] = v; acc1[0] += v;
    }
    block_reduce<1>(acc1, s_red, s_bc);
    const float spe_scale = speech_budget / fmaxf(s_bc[0], 1e-6f);

    // ---- Phase 3c: pause scores (register-resident)
    float ps[EPT];
#pragma unroll
    for (int i = 0; i < EPT; i++) {
        int t = i * NTH + tid;
        float v = 0.f;
        if (t < L) {
            float z0 = (t0r[i] - mean0) * istd0;
            float seed = 1.1f * z0 + 1.5f * rb[i] + pcoef * sp[i];
            v = expf(seed);
        }
        ps[i] = v;
    }

    // ---- Phase 4: exact radix-select of k-th largest (positive floats: bits are monotonic)
    unsigned pref = 0u, cmask = 0u;
    unsigned kk = (unsigned)kint;
    unsigned cnt_eq = 0u;
#pragma unroll 1
    for (int r = 0; r < 4; r++) {
        const int shift = 24 - 8 * r;
        for (int j = tid; j < NW * 256; j += NTH) s_hist[j] = 0u;
        __syncthreads();
#pragma unroll
        for (int i = 0; i < EPT; i++) {
            unsigned b = __float_as_uint(ps[i]);
            if ((b & cmask) == pref)
                atomicAdd(&s_hist[wid * 256 + ((b >> shift) & 0xFFu)], 1u);
        }
        __syncthreads();
        unsigned colsum = 0u;
        if (tid < 256) {
#pragma unroll
            for (int w = 0; w < NW; w++) colsum += s_hist[w * 256 + tid];
        }
        __syncthreads();
        if (tid < 256) s_hist[tid] = colsum;
        __syncthreads();
        if (wid == 0) {  // wave-0 suffix scan of 256 bins (4 bins/lane)
            unsigned base = lane * 4;
            unsigned h0 = s_hist[base + 0], h1 = s_hist[base + 1];
            unsigned h2 = s_hist[base + 2], h3 = s_hist[base + 3];
            unsigned s = h0 + h1 + h2 + h3;
            unsigned v = s;
#pragma unroll
            for (int off = 1; off < 64; off <<= 1) {
                unsigned u = __shfl_down(v, off);
                if (lane + off < 64) v += u;
            }
            unsigned vnext = __shfl_down(v, 1);
            if (lane == 63) vnext = 0u;
            unsigned higher = v - s;
            unsigned S3 = higher + h3;
            unsigned S2 = S3 + h2;
            unsigned S1 = S2 + h1;
            unsigned S0 = S1 + h0;
            if (S3 >= kk && vnext < kk)      { s_sel[0] = base + 3; s_sel[1] = vnext; s_sel[2] = S3; }
            else if (S2 >= kk && S3 < kk)    { s_sel[0] = base + 2; s_sel[1] = S3;    s_sel[2] = S2; }
            else if (S1 >= kk && S2 < kk)    { s_sel[0] = base + 1; s_sel[1] = S2;    s_sel[2] = S1; }
            else if (S0 >= kk && S1 < kk)    { s_sel[0] = base + 0; s_sel[1] = S1;    s_sel[2] = S0; }
        }
        __syncthreads();
        pref |= s_sel[0] << shift;
        cmask |= 0xFFu << shift;
        kk -= s_sel[1];
        if (r == 3) cnt_eq = s_sel[2] - s_sel[1];
        __syncthreads();
    }
    const unsigned thr_bits = pref;
    const unsigned keep_eq = kk;   // how many ==thr to keep, ascending index

    // ---- Phase 5: keep top-k (stable tie-break only if ties exist), sum kept
    float accp[1] = {0.f};
    if (cnt_eq == keep_eq) {
#pragma unroll
        for (int c = 0; c < EPT; c++) {
            unsigned b = __float_as_uint(ps[c]);
            float v = (b >= thr_bits) ? ps[c] : 0.f;
            ps[c] = v; accp[0] += v;
        }
    } else {
        unsigned carry_eq = 0u;
#pragma unroll
        for (int c = 0; c < EPT; c++) {
            unsigned b = __float_as_uint(ps[c]);
            bool eq = (b == thr_bits);
            unsigned long long bal = __ballot(eq);
            unsigned lpre = (unsigned)__popcll(bal & ((1ull << lane) - 1ull));
            unsigned wc = (unsigned)__popcll(bal);
            if (lane == 0) s_wu[wid] = wc;
            __syncthreads();
            unsigned woff = 0u, tot = 0u;
#pragma unroll
            for (int w = 0; w < NW; w++) { unsigned x = s_wu[w]; if (w < wid) woff += x; tot += x; }
            __syncthreads();
            unsigned rank = carry_eq + woff + lpre;
            bool keep = (b > thr_bits) || (eq && rank < keep_eq);
            float v = keep ? ps[c] : 0.f;
            ps[c] = v; accp[0] += v;
            carry_eq += tot;
        }
    }
    block_reduce<1>(accp, s_red, s_bc);
    const float pa_scale = pause_budget / fmaxf(s_bc[0], 1e-6f);

    // ---- Phase 6: writes + prefix scan (clock/backlog)
    const float inv_alloc = 1.f / fmaxf(speech_budget + pause_budget, 1e-6f);
    float carry = 0.f;
#pragma unroll
    for (int c = 0; c < EPT; c++) {
        int t = c * NTH + tid;
        bool in = t < L;
        float spe = sm[c] * spe_scale;
        float pae = ps[c] * pa_scale;
        o_spe[rbase + t] = spe;
        o_pae[rbase + t] = pae;
        o_al[rbase + t] = (spe + pae) * inv_alloc;
        float x = in ? (spe + pae - durr[c]) : 0.f;
#pragma unroll
        for (int off = 1; off < 64; off <<= 1) {
            float u = __shfl_up(x, off);
            if (lane >= off) x += u;
        }
        if (lane == 63) s_red[wid] = x;
        __syncthreads();
        float woff = 0.f, tot = 0.f;
#pragma unroll
        for (int w = 0; w < NW; w++) { float y = s_red[w]; if (w < wid) woff += y; tot += y; }
        __syncthreads();
        float incl = carry + woff + x;
        o_pc[rbase + t] = in ? incl : 0.f;
        o_bk[rbase + t] = in ? fmaxf(incl, 0.f) : 0.f;
        carry += tot;
    }

    if (tid == 0) {
        o_sb[row] = speech_budget;
        o_pb[row] = pause_budget;
        o_cf[row] = conf;
    }
}

extern "C" void kernel_launch(void* const* d_in, const int* in_sizes, int n_in,
                              void* d_out, int out_size, void* d_ws, size_t ws_size,
                              hipStream_t stream) {
    const float* dur   = (const float*)d_in[0];
    const float* stats = (const float*)d_in[1];
    const float* trace = (const float*)d_in[2];
    const float* mask  = (const float*)d_in[3];
    const float* cue   = (const float*)d_in[4];
    float* out = (float*)d_out;
    float* ws  = (float*)d_ws;

    ratio_kernel<<<dim3(1), dim3(BATCH), 0, stream>>>(stats, ws);
    teacher_kernel<<<dim3(BATCH), dim3(NTH), 0, stream>>>(dur, stats, trace, mask, cue, ws, out);
}